// Round 1
// baseline (406.018 us; speedup 1.0000x reference)
//
#include <hip/hip_runtime.h>
#include <stdint.h>

// BinaryLinearLayer: out = sign(x) @ sign(w), x:[8192,4096] f32, w:[4096,4096] f32.
// Exact path via i8 MFMA (K-sums <= 4096, exact in i32).
// This round: bgemm rebuilt from the 128^2 2-barrier (m97) structure (~19% of
// i8 peak) to the 256^2 8-wave 4-phase schedule: counted vmcnt (T3+T4), LDS
// XOR swizzle with inverse-swizzled global_load_lds sources (T2, rule #21),
// s_setprio around the MFMA cluster (T5). Raw s_barrier everywhere in the
// K-loop (no __syncthreads -> no forced vmcnt(0) drain).

#define DIN  4096
#define DOUT 4096
#define BM   256
#define BN   256
#define BK   128            // i8 k-elems per LDS K-tile = 128B rows
#define NT   (DIN / BK)     // 32 K-tiles

typedef __attribute__((ext_vector_type(4))) int v4i;
typedef unsigned int u32;

__device__ __forceinline__ void cp16(void* lds, const void* g) {
    __builtin_amdgcn_global_load_lds((const __attribute__((address_space(1))) u32*)g,
                                     (__attribute__((address_space(3))) u32*)lds,
                                     16, 0, 0);
}

// ---- x [N,DIN] f32 -> xb [N,DIN] i8 (+1/-1), fully coalesced ----
__global__ __launch_bounds__(256) void pack_x_i8(const float* __restrict__ x,
                                                 signed char* __restrict__ xb) {
    size_t i = (size_t)blockIdx.x * 256 + threadIdx.x;
    float4 v = ((const float4*)x)[i];
    char4 s;
    s.x = v.x >= 0.f ? 1 : -1;
    s.y = v.y >= 0.f ? 1 : -1;
    s.z = v.z >= 0.f ? 1 : -1;
    s.w = v.w >= 0.f ? 1 : -1;
    ((char4*)xb)[i] = s;
}

// ---- w [DIN,DOUT] f32 -> wbT [DOUT,DIN] i8: wbT[n][k] = sign(w[k][n]) ----
__global__ __launch_bounds__(256) void pack_wT_i8(const float* __restrict__ w,
                                                  signed char* __restrict__ wbT) {
    __shared__ signed char tile[64][80];   // stride 80: 16B-aligned rows, breaks pow2
    const int k0 = blockIdx.y * 64, n0 = blockIdx.x * 64;
    const int t = threadIdx.x;
    const int j  = t & 63;    // n offset
    const int i0 = t >> 6;    // 0..3
    #pragma unroll
    for (int s = 0; s < 16; s++) {
        int i = i0 + s * 4;   // k offset
        float v = w[(size_t)(k0 + i) * DOUT + n0 + j];
        tile[j][i] = v >= 0.f ? 1 : -1;
    }
    __syncthreads();
    const int n  = t >> 2;          // 0..63
    const int kk = (t & 3) * 16;    // byte offset within row
    v4i val = *(const v4i*)&tile[n][kk];
    *(v4i*)&wbT[(size_t)(n0 + n) * DIN + k0 + kk] = val;
}

// ---- 256^2 8-wave 4-phase i8 MFMA GEMM ----
// 512 thr = 8 waves (2M x 4N); per-wave C = 128x64 = 8x4 frags of 16x16.
// Phase p: quadrant = frag-rows {2p,2p+1} x all 4 cols x 2 k-steps = 16 MFMA.
// Per phase: 12 ds_read_b128 (4 A + 8 B, swizzle-conflict-free) + 2 prefetch
// global_load_lds units for K-tile t+1. Stage order per tile:
// [B0,B64,B128,B192,A0,A128,A64,A192]; vmcnt(4) @p1-end (gates A64/A192 of
// current tile before p2 reads them), vmcnt(2) @p3-end (leaves next tile's
// A64/A192 in flight across the flip -- not read until its p2).
__global__ __launch_bounds__(512, 2) void bgemm_i8(const signed char* __restrict__ xb,
                                                   const signed char* __restrict__ wbT,
                                                   float* __restrict__ out) {
    __shared__ __align__(16) signed char As[2][BM * BK];   // 2 x 32 KB
    __shared__ __align__(16) signed char Bs[2][BN * BK];   // 2 x 32 KB  (128 KB total)

    const int t = threadIdx.x;
    const int l = t & 63;
    const int w = t >> 6;          // 8 waves
    const int wr = w & 1;          // A half: rows wr*128..wr*128+127
    const int wc = w >> 1;         // B band: rows wc*64..wc*64+63
    const int m = l & 15, quad = l >> 4;
    const int sw = (m & 7) << 4;   // read-side XOR swizzle (involution per row)

    const int bm = blockIdx.y * BM, bn = blockIdx.x * BN;
    const signed char* gA = xb  + (size_t)bm * DIN;
    const signed char* gB = wbT + (size_t)bn * DIN;

    // stage geometry: one cp16 per thread per 64-row x 128B unit (8 KB).
    // LDS dest linear (wave-uniform base + lane*16); source col pre-swizzled
    // so that LDS[row][c] = global[row][c ^ ((row&7)<<4)]  (both-sides rule).
    const int    sr   = t >> 3;                                  // row in unit
    const size_t soff = (size_t)sr * DIN + (((t & 7) ^ (sr & 7)) * 16);
    const int    ldst = t * 16;

#define SU(lbuf, gmat, r0, kk) \
    cp16(&(lbuf)[(r0) * BK + ldst], (gmat) + (size_t)(r0) * DIN + (size_t)(kk) + soff)

    v4i acc[8][4];
    #pragma unroll
    for (int i = 0; i < 8; i++)
        #pragma unroll
        for (int j = 0; j < 4; j++) {
            v4i z = {0, 0, 0, 0};
            acc[i][j] = z;
        }

    // prologue: K-tile 0 -> buf 0 (same unit order as steady state), full drain
    SU(Bs[0], gB, 0, 0);   SU(Bs[0], gB, 64, 0);
    SU(Bs[0], gB, 128, 0); SU(Bs[0], gB, 192, 0);
    SU(As[0], gA, 0, 0);   SU(As[0], gA, 128, 0);
    SU(As[0], gA, 64, 0);  SU(As[0], gA, 192, 0);
    asm volatile("s_waitcnt vmcnt(0)" ::: "memory");
    __builtin_amdgcn_s_barrier();

    for (int kt = 0; kt < NT - 1; ++kt) {
        const int cur = kt & 1, nxt = cur ^ 1;
        const int kk = (kt + 1) * BK;
        #pragma unroll
        for (int p = 0; p < 4; ++p) {
            // 12 ds_reads from buf[cur]; addr = row*128 + (kcol ^ ((row&7)<<4))
            v4i a[2][2], b[2][4];
            #pragma unroll
            for (int i = 0; i < 2; ++i) {
                const signed char* rp = &As[cur][(wr * 128 + (2 * p + i) * 16 + m) * BK];
                a[0][i] = *(const v4i*)(rp + ((quad * 16) ^ sw));
                a[1][i] = *(const v4i*)(rp + ((64 + quad * 16) ^ sw));
            }
            #pragma unroll
            for (int j = 0; j < 4; ++j) {
                const signed char* rp = &Bs[cur][(wc * 64 + j * 16 + m) * BK];
                b[0][j] = *(const v4i*)(rp + ((quad * 16) ^ sw));
                b[1][j] = *(const v4i*)(rp + ((64 + quad * 16) ^ sw));
            }
            // prefetch 2 units of K-tile kt+1 into buf[nxt]
            if (p == 0) { SU(Bs[nxt], gB, 0, kk);   SU(Bs[nxt], gB, 64, kk); }
            if (p == 1) { SU(Bs[nxt], gB, 128, kk); SU(Bs[nxt], gB, 192, kk); }
            if (p == 2) { SU(As[nxt], gA, 0, kk);   SU(As[nxt], gA, 128, kk); }
            if (p == 3) { SU(As[nxt], gA, 64, kk);  SU(As[nxt], gA, 192, kk); }

            __builtin_amdgcn_s_barrier();
            asm volatile("s_waitcnt lgkmcnt(0)" ::: "memory");
            __builtin_amdgcn_sched_barrier(0);
            __builtin_amdgcn_s_setprio(1);
            #pragma unroll
            for (int ks = 0; ks < 2; ++ks)
                #pragma unroll
                for (int i = 0; i < 2; ++i)
                    #pragma unroll
                    for (int j = 0; j < 4; ++j)
                        acc[2 * p + i][j] = __builtin_amdgcn_mfma_i32_16x16x64_i8(
                            a[ks][i], b[ks][j], acc[2 * p + i][j], 0, 0, 0);
            __builtin_amdgcn_s_setprio(0);
            __builtin_amdgcn_sched_barrier(0);
            if (p == 1) asm volatile("s_waitcnt vmcnt(4)" ::: "memory");
            if (p == 3) asm volatile("s_waitcnt vmcnt(2)" ::: "memory");
            __builtin_amdgcn_s_barrier();
        }
    }

    // peeled last K-tile (no prefetch; drain leftover A64/A192 before p2)
    {
        const int cur = (NT - 1) & 1;
        #pragma unroll
        for (int p = 0; p < 4; ++p) {
            v4i a[2][2], b[2][4];
            #pragma unroll
            for (int i = 0; i < 2; ++i) {
                const signed char* rp = &As[cur][(wr * 128 + (2 * p + i) * 16 + m) * BK];
                a[0][i] = *(const v4i*)(rp + ((quad * 16) ^ sw));
                a[1][i] = *(const v4i*)(rp + ((64 + quad * 16) ^ sw));
            }
            #pragma unroll
            for (int j = 0; j < 4; ++j) {
                const signed char* rp = &Bs[cur][(wc * 64 + j * 16 + m) * BK];
                b[0][j] = *(const v4i*)(rp + ((quad * 16) ^ sw));
                b[1][j] = *(const v4i*)(rp + ((64 + quad * 16) ^ sw));
            }
            __builtin_amdgcn_s_barrier();
            asm volatile("s_waitcnt lgkmcnt(0)" ::: "memory");
            __builtin_amdgcn_sched_barrier(0);
            __builtin_amdgcn_s_setprio(1);
            #pragma unroll
            for (int ks = 0; ks < 2; ++ks)
                #pragma unroll
                for (int i = 0; i < 2; ++i)
                    #pragma unroll
                    for (int j = 0; j < 4; ++j)
                        acc[2 * p + i][j] = __builtin_amdgcn_mfma_i32_16x16x64_i8(
                            a[ks][i], b[ks][j], acc[2 * p + i][j], 0, 0, 0);
            __builtin_amdgcn_s_setprio(0);
            __builtin_amdgcn_sched_barrier(0);
            if (p == 1) asm volatile("s_waitcnt vmcnt(0)" ::: "memory");
            __builtin_amdgcn_s_barrier();
        }
    }
#undef SU

    // epilogue: C/D col=lane&15, row=quad*4+reg (HW-verified, dtype-independent)
    #pragma unroll
    for (int i = 0; i < 8; i++) {
        int row0 = bm + wr * 128 + i * 16 + quad * 4;
        #pragma unroll
        for (int j = 0; j < 4; j++) {
            int col = bn + wc * 64 + j * 16 + m;
            #pragma unroll
            for (int r = 0; r < 4; r++)
                out[(size_t)(row0 + r) * DOUT + col] = (float)acc[i][j][r];
        }
    }
}

extern "C" void kernel_launch(void* const* d_in, const int* in_sizes, int n_in,
                              void* d_out, int out_size, void* d_ws, size_t ws_size,
                              hipStream_t stream) {
    const float* x = (const float*)d_in[0];
    const float* w = (const float*)d_in[1];
    float* out = (float*)d_out;
    const int N = in_sizes[0] / DIN;                       // 8192

    signed char* xb  = (signed char*)d_ws;                 // 32 MB
    signed char* wbT = (signed char*)d_ws + (size_t)N * DIN;  // 16 MB

    pack_x_i8<<<(N * DIN) / 1024, 256, 0, stream>>>(x, xb);
    pack_wT_i8<<<dim3(DOUT / 64, DIN / 64), 256, 0, stream>>>(w, wbT);
    bgemm_i8<<<dim3(DOUT / BN, N / BM), 512, 0, stream>>>(xb, wbT, out);
}

// Round 2
// 399.354 us; speedup vs baseline: 1.0167x; 1.0167x over previous
//
#include <hip/hip_runtime.h>
#include <stdint.h>

// BinaryLinearLayer: out = sign(x) @ sign(w), x:[8192,4096] f32, w:[4096,4096] f32.
// Exact path via i8 MFMA (K-sums <= 4096, exact in i32).
// R2: 32x32x32 i8 MFMA (4404 TOPS ubench vs 3944 for 16x16x64; 2x arith
// intensity per LDS byte -> ds_reads halved; 2 phases/K-tile -> barriers
// halved), XCD-aware block swizzle (FETCH 147MB vs ~50MB ideal = L2 thrash),
// vectorized packs (pack_wT was scalar-f32 reads, G13).

#define DIN  4096
#define DOUT 4096
#define BM   256
#define BN   256
#define BK   128            // i8 k-elems per LDS K-tile = 128B rows
#define NT   (DIN / BK)     // 32 K-tiles

typedef __attribute__((ext_vector_type(4)))  int v4i;
typedef __attribute__((ext_vector_type(16))) int v16i;
typedef unsigned int u32;

__device__ __forceinline__ void cp16(void* lds, const void* g) {
    __builtin_amdgcn_global_load_lds((const __attribute__((address_space(1))) u32*)g,
                                     (__attribute__((address_space(3))) u32*)lds,
                                     16, 0, 0);
}

// ---- x [N,DIN] f32 -> xb [N,DIN] i8 (+1/-1): 64B read / 16B write per thread ----
__global__ __launch_bounds__(256) void pack_x_i8(const float* __restrict__ x,
                                                 signed char* __restrict__ xb) {
    size_t g = (size_t)blockIdx.x * 256 + threadIdx.x;   // 16-float group index
    const float4* xv = (const float4*)x + g * 4;
    v4i o;
    #pragma unroll
    for (int q = 0; q < 4; q++) {
        float4 v = xv[q];
        int c0 = v.x >= 0.f ? 1 : 0xFF;
        int c1 = v.y >= 0.f ? 1 : 0xFF;
        int c2 = v.z >= 0.f ? 1 : 0xFF;
        int c3 = v.w >= 0.f ? 1 : 0xFF;
        o[q] = c0 | (c1 << 8) | (c2 << 16) | (c3 << 24);
    }
    ((v4i*)xb)[g] = o;
}

// ---- w [DIN,DOUT] f32 -> wbT [DOUT,DIN] i8: wbT[n][k] = sign(w[k][n]) ----
// float4 reads along n (G13), 64x64 tile transpose through LDS.
__global__ __launch_bounds__(256) void pack_wT_i8(const float* __restrict__ w,
                                                  signed char* __restrict__ wbT) {
    __shared__ signed char tile[64][80];   // stride 80: 16B-aligned rows, breaks pow2
    const int k0 = blockIdx.y * 64, n0 = blockIdx.x * 64;
    const int t = threadIdx.x;
    const int j4 = (t & 15) * 4;    // n offset (float4)
    const int i0 = t >> 4;          // k row 0..15
    #pragma unroll
    for (int s = 0; s < 4; s++) {
        int i = i0 + s * 16;        // k offset
        float4 v = *(const float4*)&w[(size_t)(k0 + i) * DOUT + n0 + j4];
        tile[j4 + 0][i] = v.x >= 0.f ? 1 : -1;
        tile[j4 + 1][i] = v.y >= 0.f ? 1 : -1;
        tile[j4 + 2][i] = v.z >= 0.f ? 1 : -1;
        tile[j4 + 3][i] = v.w >= 0.f ? 1 : -1;
    }
    __syncthreads();
    const int n  = t >> 2;          // 0..63
    const int kk = (t & 3) * 16;    // byte offset within row
    v4i val = *(const v4i*)&tile[n][kk];
    *(v4i*)&wbT[(size_t)(n0 + n) * DIN + k0 + kk] = val;
}

// ---- 256^2 8-wave 2-phase/K-tile i8 MFMA GEMM (32x32x32) ----
// 512 thr = 8 waves (2M x 4N); per-wave C = 128x64 = 4x2 frags of 32x32.
// Phase p covers m-frags {2p,2p+1} x 2 n-frags x 4 k-steps = 16 MFMA.
// B frags (8 ds_read) loaded in p0, live across p1. Per phase: 8-16 ds_read +
// 4 prefetch global_load_lds + 2 barriers. Issue order per tile:
// p0:[B0,B64,B128,B192] p1:[A0,A128,A64,A192]; vmcnt(4) @p0-end gates current
// tile's A64/A192; vmcnt(2) @p1-end leaves next tile's A64/A192 in flight.
// Frag layout (extrapolated bf16->i8 exactly as the verified 16x16 kernel):
// A/B lane l: 16B @ row l&31, kbyte (l>>5)*16; C/D col=l&31,
// row=(reg&3)+8*(reg>>2)+4*(l>>5)  (shape-determined, dtype-independent).
__global__ __launch_bounds__(512, 2) void bgemm_i8(const signed char* __restrict__ xb,
                                                   const signed char* __restrict__ wbT,
                                                   float* __restrict__ out) {
    __shared__ __align__(16) signed char As[2][BM * BK];   // 2 x 32 KB
    __shared__ __align__(16) signed char Bs[2][BN * BK];   // 2 x 32 KB  (128 KB)

    const int t = threadIdx.x;
    const int l = t & 63;
    const int w = t >> 6;          // 8 waves
    const int wr = w & 1;          // A half: rows wr*128..+127
    const int wc = w >> 1;         // B band: rows wc*64..+63
    const int lm = l & 31;         // frag row lane
    const int hi = l >> 5;         // k-half
    const int sw = (lm & 7) << 4;  // read-side XOR swizzle (row&7 == lm&7: frag bases %32==0)

    // XCD-aware bijective swizzle (512 blocks % 8 == 0): each XCD gets a
    // contiguous chunk of bm-major order -> A-panel L2 reuse.
    const int fid = blockIdx.y * gridDim.x + blockIdx.x;
    const int swz = (fid & 7) * 64 + (fid >> 3);
    const int bm = (swz >> 4) * BM, bn = (swz & 15) * BN;

    const signed char* gA = xb  + (size_t)bm * DIN;
    const signed char* gB = wbT + (size_t)bn * DIN;

    // staging: one cp16/thread per 64-row x 128B unit (8 KB); LDS dest linear,
    // global source col pre-swizzled (both-sides rule):
    // LDS[row][c] = global[row][c ^ ((row&7)<<4)]
    const int    sr   = t >> 3;
    const size_t soff = (size_t)sr * DIN + (((t & 7) ^ (sr & 7)) * 16);
    const int    ldst = t * 16;

#define SU(lbuf, gmat, r0, kk) \
    cp16(&(lbuf)[(r0) * BK + ldst], (gmat) + (size_t)(r0) * DIN + (size_t)(kk) + soff)

    v16i acc[4][2];
    #pragma unroll
    for (int i = 0; i < 4; i++)
        #pragma unroll
        for (int j = 0; j < 2; j++)
            #pragma unroll
            for (int r = 0; r < 16; r++)
                acc[i][j][r] = 0;

    // prologue: K-tile 0 -> buf 0 (steady-state unit order); leave A64/A192 in flight
    SU(Bs[0], gB, 0, 0);   SU(Bs[0], gB, 64, 0);
    SU(Bs[0], gB, 128, 0); SU(Bs[0], gB, 192, 0);
    SU(As[0], gA, 0, 0);   SU(As[0], gA, 128, 0);
    SU(As[0], gA, 64, 0);  SU(As[0], gA, 192, 0);
    asm volatile("s_waitcnt vmcnt(2)" ::: "memory");
    __builtin_amdgcn_s_barrier();

    v4i b[2][4];   // B frags, read in p0, live across the whole K-tile

    for (int kt = 0; kt < NT - 1; ++kt) {
        const int cur = kt & 1, nxt = cur ^ 1;
        const int kk = (kt + 1) * BK;
        #pragma unroll
        for (int p = 0; p < 2; ++p) {
            v4i a[2][4];
            #pragma unroll
            for (int i = 0; i < 2; ++i) {   // m-frag 2p+i, rows wr*128+(2p+i)*32+lm
                const signed char* rp = &As[cur][(wr * 128 + (2 * p + i) * 32 + lm) * BK];
                #pragma unroll
                for (int ks = 0; ks < 4; ++ks)
                    a[i][ks] = *(const v4i*)(rp + ((ks * 32 + hi * 16) ^ sw));
            }
            if (p == 0) {
                #pragma unroll
                for (int j = 0; j < 2; ++j) {
                    const signed char* rp = &Bs[cur][(wc * 64 + j * 32 + lm) * BK];
                    #pragma unroll
                    for (int ks = 0; ks < 4; ++ks)
                        b[j][ks] = *(const v4i*)(rp + ((ks * 32 + hi * 16) ^ sw));
                }
                SU(Bs[nxt], gB, 0, kk);   SU(Bs[nxt], gB, 64, kk);
                SU(Bs[nxt], gB, 128, kk); SU(Bs[nxt], gB, 192, kk);
            } else {
                SU(As[nxt], gA, 0, kk);   SU(As[nxt], gA, 128, kk);
                SU(As[nxt], gA, 64, kk);  SU(As[nxt], gA, 192, kk);
            }

            __builtin_amdgcn_s_barrier();
            asm volatile("s_waitcnt lgkmcnt(0)" ::: "memory");
            __builtin_amdgcn_sched_barrier(0);
            __builtin_amdgcn_s_setprio(1);
            #pragma unroll
            for (int ks = 0; ks < 4; ++ks)
                #pragma unroll
                for (int i = 0; i < 2; ++i)
                    #pragma unroll
                    for (int j = 0; j < 2; ++j)
                        acc[2 * p + i][j] = __builtin_amdgcn_mfma_i32_32x32x32_i8(
                            a[i][ks], b[j][ks], acc[2 * p + i][j], 0, 0, 0);
            __builtin_amdgcn_s_setprio(0);
            __builtin_amdgcn_sched_barrier(0);
            if (p == 0) asm volatile("s_waitcnt vmcnt(4)" ::: "memory");
            else        asm volatile("s_waitcnt vmcnt(2)" ::: "memory");
            __builtin_amdgcn_s_barrier();
        }
    }

    // peeled last K-tile (no prefetch; drain A64/A192 before p1 reads them)
    {
        const int cur = (NT - 1) & 1;
        #pragma unroll
        for (int p = 0; p < 2; ++p) {
            v4i a[2][4];
            #pragma unroll
            for (int i = 0; i < 2; ++i) {
                const signed char* rp = &As[cur][(wr * 128 + (2 * p + i) * 32 + lm) * BK];
                #pragma unroll
                for (int ks = 0; ks < 4; ++ks)
                    a[i][ks] = *(const v4i*)(rp + ((ks * 32 + hi * 16) ^ sw));
            }
            if (p == 0) {
                #pragma unroll
                for (int j = 0; j < 2; ++j) {
                    const signed char* rp = &Bs[cur][(wc * 64 + j * 32 + lm) * BK];
                    #pragma unroll
                    for (int ks = 0; ks < 4; ++ks)
                        b[j][ks] = *(const v4i*)(rp + ((ks * 32 + hi * 16) ^ sw));
                }
            }
            __builtin_amdgcn_s_barrier();
            asm volatile("s_waitcnt lgkmcnt(0)" ::: "memory");
            __builtin_amdgcn_sched_barrier(0);
            __builtin_amdgcn_s_setprio(1);
            #pragma unroll
            for (int ks = 0; ks < 4; ++ks)
                #pragma unroll
                for (int i = 0; i < 2; ++i)
                    #pragma unroll
                    for (int j = 0; j < 2; ++j)
                        acc[2 * p + i][j] = __builtin_amdgcn_mfma_i32_32x32x32_i8(
                            a[i][ks], b[j][ks], acc[2 * p + i][j], 0, 0, 0);
            __builtin_amdgcn_s_setprio(0);
            __builtin_amdgcn_sched_barrier(0);
            if (p == 0) asm volatile("s_waitcnt vmcnt(0)" ::: "memory");
            __builtin_amdgcn_s_barrier();
        }
    }
#undef SU

    // epilogue: C/D col=l&31, row=(r&3)+8*(r>>2)+4*hi (shape-determined)
    #pragma unroll
    for (int f = 0; f < 4; f++) {
        #pragma unroll
        for (int g = 0; g < 2; g++) {
            int col = bn + wc * 64 + g * 32 + lm;
            #pragma unroll
            for (int r = 0; r < 16; r++) {
                int row = bm + wr * 128 + f * 32 + (r & 3) + 8 * (r >> 2) + 4 * hi;
                out[(size_t)row * DOUT + col] = (float)acc[f][g][r];
            }
        }
    }
}

extern "C" void kernel_launch(void* const* d_in, const int* in_sizes, int n_in,
                              void* d_out, int out_size, void* d_ws, size_t ws_size,
                              hipStream_t stream) {
    const float* x = (const float*)d_in[0];
    const float* w = (const float*)d_in[1];
    float* out = (float*)d_out;
    const int N = in_sizes[0] / DIN;                       // 8192

    signed char* xb  = (signed char*)d_ws;                 // 32 MB
    signed char* wbT = (signed char*)d_ws + (size_t)N * DIN;  // 16 MB

    pack_x_i8<<<(N * DIN) / (16 * 256), 256, 0, stream>>>(x, xb);
    pack_wT_i8<<<dim3(DOUT / 64, DIN / 64), 256, 0, stream>>>(w, wbT);
    bgemm_i8<<<dim3(DOUT / BN, N / BM), 512, 0, stream>>>(xb, wbT, out);
}